// Round 8
// baseline (76.878 us; speedup 1.0000x reference)
//
#include <hip/hip_runtime.h>

#define DIVN 8
#define NB 32
#define NBLK 6144                 // 96 images * 64 blocks
#define NBAND 768                 // img*8 + bi  (128-row bands)

typedef float floatx4 __attribute__((ext_vector_type(4)));

// Stage 1: each WG (512 threads) owns a contiguous 512 KB band (128 rows of
// one image = one full block-row). Thread tid reads float4-column (tid&255)
// in row-half (tid>>8); its bj = (tid&255)>>5 is FIXED -> scalar accumulators,
// shfl reduce within 32-lane groups, tiny LDS exchange to combine halves,
// final packed float4{mean,min,max,0} per block.
// PLAIN loads (no nontemporal hint): let the memory-side Infinity Cache
// retain what it can across graph replays.
__global__ __launch_bounds__(512) void stats_kernel(
    const float* __restrict__ x,
    floatx4* __restrict__ stats) {    // [NBLK]
    const int ch  = blockIdx.x;            // 0..767
    const int tid = threadIdx.x;           // 0..511
    const int col = tid & 255;             // float4 column
    const int rh  = tid >> 8;              // row half 0/1
    const float* base = x + (size_t)ch * (128 * 1024) + (size_t)rh * (64 * 1024) + col * 4;

    double s = 0.0;
    float mn = 3.402823466e38f;
    float mx = -3.402823466e38f;

    #pragma unroll 8
    for (int i = 0; i < 64; ++i) {
        const floatx4 v = *reinterpret_cast<const floatx4*>(base + (size_t)i * 1024);
        s += (double)((v.x + v.y) + (v.z + v.w));
        mn = fminf(mn, fminf(fminf(v.x, v.y), fminf(v.z, v.w)));
        mx = fmaxf(mx, fmaxf(fmaxf(v.x, v.y), fmaxf(v.z, v.w)));
    }

    // Reduce within 32-lane groups (one group per (bj, half)).
    for (int off = 16; off > 0; off >>= 1) {
        s  += __shfl_down(s, off, 32);
        mn  = fminf(mn, __shfl_down(mn, off, 32));
        mx  = fmaxf(mx, __shfl_down(mx, off, 32));
    }

    __shared__ double lsum[16];
    __shared__ float  lmn[16], lmx[16];
    if ((tid & 31) == 0) {
        const int g = tid >> 5;            // 0..15 : (half<<3) | bj
        lsum[g] = s; lmn[g] = mn; lmx[g] = mx;
    }
    __syncthreads();

    if (tid < 8) {                          // tid = bj
        const double st = lsum[tid] + lsum[tid + 8];     // half0 + half1, fixed order
        floatx4 r;
        r.x = (float)(st * (1.0 / 16384.0));
        r.y = fminf(lmn[tid], lmn[tid + 8]);
        r.z = fmaxf(lmx[tid], lmx[tid + 8]);
        r.w = 0.0f;
        const int img = ch >> 3;
        const int bi  = ch & 7;
        stats[img * 64 + bi * 8 + tid] = r;
    }
}

// Stage 2: single WG; 98 KB of packed stats, 24 independent float4 loads
// per thread, pair terms, LDS tree reduce.
__global__ __launch_bounds__(256) void pair_reduce_kernel(
    const floatx4* __restrict__ stats,
    float* __restrict__ out) {
    const int tid = threadIdx.x;
    double acc = 0.0;

    for (int item = tid; item < NB * 64; item += 256) {
        const int p = item & 63;        // bi*8 + bj
        const int b = item >> 6;
        const floatx4 s0 = stats[(b * 3 + 0) * 64 + p];
        const floatx4 s1 = stats[(b * 3 + 1) * 64 + p];
        const floatx4 s2 = stats[(b * 3 + 2) * 64 + p];

        if (!((s0.y > s1.z) || (s0.z < s1.y))) { const float d = s0.x - s1.x; acc += (double)(d * d); }
        if (!((s1.y > s2.z) || (s1.z < s2.y))) { const float d = s1.x - s2.x; acc += (double)(d * d); }
        if (!((s0.y > s2.z) || (s0.z < s2.y))) { const float d = s0.x - s2.x; acc += (double)(d * d); }
    }

    __shared__ double sacc[256];
    sacc[tid] = acc;
    __syncthreads();
    for (int off = 128; off > 0; off >>= 1) {
        if (tid < off) sacc[tid] += sacc[tid + off];
        __syncthreads();
    }
    if (tid == 0) out[0] = (float)(sacc[0] * (1.0 / (DIVN * DIVN)));
}

extern "C" void kernel_launch(void* const* d_in, const int* in_sizes, int n_in,
                              void* d_out, int out_size, void* d_ws, size_t ws_size,
                              hipStream_t stream) {
    const float* x = (const float*)d_in[0];
    float* out = (float*)d_out;
    floatx4* stats = (floatx4*)d_ws;     // NBLK float4 = 98304 B

    stats_kernel<<<NBAND, 512, 0, stream>>>(x, stats);
    pair_reduce_kernel<<<1, 256, 0, stream>>>(stats, out);
}

// Round 9
// 66.804 us; speedup vs baseline: 1.1508x; 1.1508x over previous
//
#include <hip/hip_runtime.h>

#define DIVN 8
#define NB 32
#define NBLK 6144                 // 96 images * 64 blocks
#define NBAND 768                 // img*8 + bi  (128-row bands)

typedef float floatx4 __attribute__((ext_vector_type(4)));

// Stage 1: each WG (512 threads) owns a contiguous 512 KB band (128 rows of
// one image = one full block-row). Thread tid reads float4-column (tid&255)
// in row-half (tid>>8); its bj = (tid&255)>>5 is FIXED -> scalar accumulators,
// shfl reduce within 32-lane groups, tiny LDS exchange to combine halves,
// final packed float4{mean,min,max,0} per block.
// NONTEMPORAL loads are required here: the 403 MB single-pass stream
// thrashes the 256 MB L3; nt skips allocate/evict churn (+13% measured, r8).
__global__ __launch_bounds__(512) void stats_kernel(
    const float* __restrict__ x,
    floatx4* __restrict__ stats) {    // [NBLK]
    const int ch  = blockIdx.x;            // 0..767
    const int tid = threadIdx.x;           // 0..511
    const int col = tid & 255;             // float4 column
    const int rh  = tid >> 8;              // row half 0/1
    const float* base = x + (size_t)ch * (128 * 1024) + (size_t)rh * (64 * 1024) + col * 4;

    double s = 0.0;
    float mn = 3.402823466e38f;
    float mx = -3.402823466e38f;

    #pragma unroll 8
    for (int i = 0; i < 64; ++i) {
        const floatx4 v = __builtin_nontemporal_load(
            reinterpret_cast<const floatx4*>(base + (size_t)i * 1024));
        s += (double)((v.x + v.y) + (v.z + v.w));
        mn = fminf(mn, fminf(fminf(v.x, v.y), fminf(v.z, v.w)));
        mx = fmaxf(mx, fmaxf(fmaxf(v.x, v.y), fmaxf(v.z, v.w)));
    }

    // Reduce within 32-lane groups (one group per (bj, half)).
    for (int off = 16; off > 0; off >>= 1) {
        s  += __shfl_down(s, off, 32);
        mn  = fminf(mn, __shfl_down(mn, off, 32));
        mx  = fmaxf(mx, __shfl_down(mx, off, 32));
    }

    __shared__ double lsum[16];
    __shared__ float  lmn[16], lmx[16];
    if ((tid & 31) == 0) {
        const int g = tid >> 5;            // 0..15 : (half<<3) | bj
        lsum[g] = s; lmn[g] = mn; lmx[g] = mx;
    }
    __syncthreads();

    if (tid < 8) {                          // tid = bj
        const double st = lsum[tid] + lsum[tid + 8];     // half0 + half1, fixed order
        floatx4 r;
        r.x = (float)(st * (1.0 / 16384.0));
        r.y = fminf(lmn[tid], lmn[tid + 8]);
        r.z = fmaxf(lmx[tid], lmx[tid + 8]);
        r.w = 0.0f;
        const int img = ch >> 3;
        const int bi  = ch & 7;
        stats[img * 64 + bi * 8 + tid] = r;
    }
}

// Stage 2: single WG; 98 KB of packed stats, 24 independent float4 loads
// per thread, pair terms, LDS tree reduce.
__global__ __launch_bounds__(256) void pair_reduce_kernel(
    const floatx4* __restrict__ stats,
    float* __restrict__ out) {
    const int tid = threadIdx.x;
    double acc = 0.0;

    for (int item = tid; item < NB * 64; item += 256) {
        const int p = item & 63;        // bi*8 + bj
        const int b = item >> 6;
        const floatx4 s0 = stats[(b * 3 + 0) * 64 + p];
        const floatx4 s1 = stats[(b * 3 + 1) * 64 + p];
        const floatx4 s2 = stats[(b * 3 + 2) * 64 + p];

        if (!((s0.y > s1.z) || (s0.z < s1.y))) { const float d = s0.x - s1.x; acc += (double)(d * d); }
        if (!((s1.y > s2.z) || (s1.z < s2.y))) { const float d = s1.x - s2.x; acc += (double)(d * d); }
        if (!((s0.y > s2.z) || (s0.z < s2.y))) { const float d = s0.x - s2.x; acc += (double)(d * d); }
    }

    __shared__ double sacc[256];
    sacc[tid] = acc;
    __syncthreads();
    for (int off = 128; off > 0; off >>= 1) {
        if (tid < off) sacc[tid] += sacc[tid + off];
        __syncthreads();
    }
    if (tid == 0) out[0] = (float)(sacc[0] * (1.0 / (DIVN * DIVN)));
}

extern "C" void kernel_launch(void* const* d_in, const int* in_sizes, int n_in,
                              void* d_out, int out_size, void* d_ws, size_t ws_size,
                              hipStream_t stream) {
    const float* x = (const float*)d_in[0];
    float* out = (float*)d_out;
    floatx4* stats = (floatx4*)d_ws;     // NBLK float4 = 98304 B

    stats_kernel<<<NBAND, 512, 0, stream>>>(x, stats);
    pair_reduce_kernel<<<1, 256, 0, stream>>>(stats, out);
}